// Round 1
// baseline (229.426 us; speedup 1.0000x reference)
//
#include <hip/hip_runtime.h>
#include <math.h>

// Problem constants (from reference)
#define NKP 133
#define NB  256
#define NROWS (NB * NKP)        // 34048 rows
#define HALF 512                // W == H == 512
#define BETA 10.0f

__global__ __launch_bounds__(256) void rtmcc_loss_kernel(
    const float* __restrict__ pred,       // [NROWS][1024]
    const float* __restrict__ keypoints,  // [NROWS][3]
    float* __restrict__ out)              // [1]
{
    const int wave = threadIdx.x >> 6;
    const int lane = threadIdx.x & 63;
    const int rh   = blockIdx.x * 4 + wave;      // row-half index in [0, 2*NROWS)
    __shared__ float partial[4];

    const int row = rh >> 1;
    const int h   = rh & 1;                      // 0 = x half, 1 = y half

    // --- keypoint / gaussian-target parameters (broadcast loads, L1-cached) ---
    const float kx  = keypoints[row * 3 + 0];
    const float ky  = keypoints[row * 3 + 1];
    const float vis = keypoints[row * 3 + 2];

    const float mux = rintf(kx * 2.0f);          // jnp.round = half-to-even = rintf
    const float muy = rintf(ky * 2.0f);
    const float rad = 5.66f * 3.0f;              // sigma*3
    const bool oob = (mux - rad >= 512.0f) || (muy - rad >= 512.0f) ||
                     (mux + rad + 1.0f < 0.0f) || (muy + rad + 1.0f < 0.0f);
    const bool visible = (vis >= 0.5f);
    const bool valid   = visible && !oob;
    const float w      = (visible && oob) ? 0.0f : vis;

    const float mu = h ? muy : mux;
    const float inv2s2 = 1.0f / (2.0f * 5.66f * 5.66f);

    // --- load 8 contiguous pred values per lane (two float4, 16B-aligned) ---
    const float* p = pred + (size_t)row * 1024 + h * HALF + lane * 8;
    const float4 pa = *reinterpret_cast<const float4*>(p);
    const float4 pb = *reinterpret_cast<const float4*>(p + 4);
    float pv[8] = {pa.x, pa.y, pa.z, pa.w, pb.x, pb.y, pb.z, pb.w};

    // --- wave max of pred ---
    float m = pv[0];
    #pragma unroll
    for (int u = 1; u < 8; ++u) m = fmaxf(m, pv[u]);
    #pragma unroll
    for (int off = 1; off < 64; off <<= 1) m = fmaxf(m, __shfl_xor(m, off, 64));
    m *= BETA;                                    // max(10*p) = 10*max(p)

    // --- accumulate S, Z, T, D ---
    float S = 0.0f, Z = 0.0f, T = 0.0f, D = 0.0f;
    #pragma unroll
    for (int u = 0; u < 8; ++u) {
        const float a = BETA * pv[u];
        S += __expf(a - m);
        const float d  = (float)(lane * 8 + u) - mu;
        const float g  = valid ? __expf(-d * d * inv2s2) : 0.0f;
        const float tg = BETA * g;
        const float e  = __expf(tg);
        Z += e;
        T += e * tg;
        D += e * pv[u];
    }
    #pragma unroll
    for (int off = 1; off < 64; off <<= 1) {
        S += __shfl_xor(S, off, 64);
        Z += __shfl_xor(Z, off, 64);
        T += __shfl_xor(T, off, 64);
        D += __shfl_xor(D, off, 64);
    }

    if (lane == 0) {
        const float loss = (T / Z - __logf(Z)) + m + __logf(S) - BETA * (D / Z);
        partial[wave] = w * loss * (1.0f / (512.0f * 133.0f));
    }
    __syncthreads();
    if (threadIdx.x == 0) {
        atomicAdd(out, partial[0] + partial[1] + partial[2] + partial[3]);
    }
}

extern "C" void kernel_launch(void* const* d_in, const int* in_sizes, int n_in,
                              void* d_out, int out_size, void* d_ws, size_t ws_size,
                              hipStream_t stream) {
    const float* pred = (const float*)d_in[0];       // (256,133,1024) fp32
    const float* kpts = (const float*)d_in[1];       // (256,133,3) fp32
    float* out = (float*)d_out;

    hipMemsetAsync(out, 0, sizeof(float), stream);

    const int row_halves = 2 * NROWS;                // 68096
    const int blocks = row_halves / 4;               // 17024, divides exactly
    rtmcc_loss_kernel<<<blocks, 256, 0, stream>>>(pred, kpts, out);
}

// Round 2
// 37.132 us; speedup vs baseline: 6.1786x; 6.1786x over previous
//
#include <hip/hip_runtime.h>
#include <math.h>

#define NKP 133
#define NB  256
#define NROWS (NB * NKP)          // 34048
#define RH_TOTAL (2 * NROWS)      // 68096 row-halves
#define BETA 10.0f
#define NBLOCKS 2048

__global__ __launch_bounds__(256) void rtmcc_partial_kernel(
    const float* __restrict__ pred,       // [NROWS][1024] == [RH_TOTAL][512]
    const float* __restrict__ keypoints,  // [NROWS][3]
    float* __restrict__ partials)         // [NBLOCKS]
{
    const int wave = threadIdx.x >> 6;
    const int lane = threadIdx.x & 63;
    const int nwaves = NBLOCKS * 4;       // 8192
    __shared__ float lds[4];

    const float inv2s2 = 1.0f / (2.0f * 5.66f * 5.66f);
    const float rad = 5.66f * 3.0f;

    float acc = 0.0f;                     // identical across lanes of a wave

    for (int rh = blockIdx.x * 4 + wave; rh < RH_TOTAL; rh += nwaves) {
        const int row = rh >> 1;
        const int h   = rh & 1;

        // broadcast keypoint loads (same addr across lanes -> 1 load, cached)
        const float kx  = keypoints[row * 3 + 0];
        const float ky  = keypoints[row * 3 + 1];
        const float vis = keypoints[row * 3 + 2];

        const float mux = rintf(kx * 2.0f);   // jnp.round = half-to-even
        const float muy = rintf(ky * 2.0f);
        const bool oob = (mux - rad >= 512.0f) || (muy - rad >= 512.0f) ||
                         (mux + rad + 1.0f < 0.0f) || (muy + rad + 1.0f < 0.0f);
        const bool visible = (vis >= 0.5f);
        const float w = (visible && oob) ? 0.0f : vis;

        if (w == 0.0f) continue;              // wave-uniform: skip loads entirely

        const bool valid = visible && !oob;   // here: always true, kept for clarity
        const float mu = h ? muy : mux;

        // 8 contiguous floats per lane: two float4 (32B/lane, fully coalesced)
        const float* p = pred + (size_t)rh * 512 + lane * 8;
        const float4 pa = *reinterpret_cast<const float4*>(p);
        const float4 pb = *reinterpret_cast<const float4*>(p + 4);
        const float pv[8] = {pa.x, pa.y, pa.z, pa.w, pb.x, pb.y, pb.z, pb.w};

        // S = sum exp(10*p); Z = sum e; T = sum e*(10*t); D = sum e*p
        float S = 0.0f, Z = 0.0f, T = 0.0f, D = 0.0f;
        #pragma unroll
        for (int u = 0; u < 8; ++u) {
            S += __expf(BETA * pv[u]);                 // |10p| < ~60, safe in fp32
            const float d  = (float)(lane * 8 + u) - mu;
            const float g  = valid ? __expf(-d * d * inv2s2) : 0.0f;
            const float tg = BETA * g;
            const float e  = __expf(tg);
            Z += e;
            T += e * tg;
            D += e * pv[u];
        }
        #pragma unroll
        for (int off = 1; off < 64; off <<= 1) {
            S += __shfl_xor(S, off, 64);
            Z += __shfl_xor(Z, off, 64);
            T += __shfl_xor(T, off, 64);
            D += __shfl_xor(D, off, 64);
        }
        // butterfly leaves full sums in ALL lanes -> redundant but uniform
        const float loss = T / Z - __logf(Z) + __logf(S) - BETA * (D / Z);
        acc += w * loss;
    }

    acc *= (1.0f / (512.0f * 133.0f));
    if (lane == 0) lds[wave] = acc;
    __syncthreads();
    if (threadIdx.x == 0)
        partials[blockIdx.x] = lds[0] + lds[1] + lds[2] + lds[3];
}

__global__ __launch_bounds__(256) void rtmcc_reduce_kernel(
    const float* __restrict__ partials, float* __restrict__ out)
{
    __shared__ float lds[4];
    float s = 0.0f;
    for (int i = threadIdx.x; i < NBLOCKS; i += 256) s += partials[i];
    #pragma unroll
    for (int off = 1; off < 64; off <<= 1) s += __shfl_xor(s, off, 64);
    if ((threadIdx.x & 63) == 0) lds[threadIdx.x >> 6] = s;
    __syncthreads();
    if (threadIdx.x == 0) out[0] = lds[0] + lds[1] + lds[2] + lds[3];
}

extern "C" void kernel_launch(void* const* d_in, const int* in_sizes, int n_in,
                              void* d_out, int out_size, void* d_ws, size_t ws_size,
                              hipStream_t stream) {
    const float* pred = (const float*)d_in[0];   // (256,133,1024) fp32
    const float* kpts = (const float*)d_in[1];   // (256,133,3) fp32
    float* out = (float*)d_out;
    float* partials = (float*)d_ws;              // NBLOCKS floats

    rtmcc_partial_kernel<<<NBLOCKS, 256, 0, stream>>>(pred, kpts, partials);
    rtmcc_reduce_kernel<<<1, 256, 0, stream>>>(partials, out);
}

// Round 3
// 30.140 us; speedup vs baseline: 7.6119x; 1.2320x over previous
//
#include <hip/hip_runtime.h>
#include <math.h>

#define NKP 133
#define NROWS (256 * NKP)         // 34048
#define RH_TOTAL (2 * NROWS)      // 68096 row-halves of 512
#define NBLOCKS 2048
#define C2P  14.4269504088896f    // 10 * log2(e)  : exp(10x) = exp2(C2P*x)
#define NK2  0.02251706f          // log2(e) / (2*5.66^2) : gaussian exponent in base 2

static __device__ __forceinline__ float fexp2(float x) {
    return __builtin_amdgcn_exp2f(x);   // raw v_exp_f32
}

__global__ __launch_bounds__(256) void rtmcc_partial_kernel(
    const float* __restrict__ pred,       // [RH_TOTAL][512]
    const float* __restrict__ keypoints,  // [NROWS][3]
    float* __restrict__ partials)         // [NBLOCKS]
{
    const int wave = threadIdx.x >> 6;
    const int lane = threadIdx.x & 63;
    const float lanef = (float)lane;
    __shared__ float lds[4];

    const float rad = 5.66f * 3.0f;
    float acc = 0.0f;

    for (int rh = blockIdx.x * 4 + wave; rh < RH_TOTAL; rh += NBLOCKS * 4) {
        const int row = rh >> 1;
        const int h   = rh & 1;

        // wave-uniform keypoint params (scalarized broadcast loads)
        const float kx  = keypoints[row * 3 + 0];
        const float ky  = keypoints[row * 3 + 1];
        const float vis = keypoints[row * 3 + 2];

        const float mux = rintf(kx * 2.0f);    // round half-to-even, matches jnp.round
        const float muy = rintf(ky * 2.0f);
        const bool oob = (mux - rad >= 512.0f) || (muy - rad >= 512.0f) ||
                         (mux + rad + 1.0f < 0.0f) || (muy + rad + 1.0f < 0.0f);
        const bool visible = (vis >= 0.5f);
        const float w = (visible && oob) ? 0.0f : vis;
        if (!(w > 0.0f)) continue;             // wave-uniform skip (zero contribution)

        const float mu = h ? muy : mux;
        const float* pr = pred + (size_t)rh * 512;

        // ---- bulk pass: all 512 elements, 8/lane, two float4 loads ----
        const float* p = pr + lane * 8;
        const float4 pa = *reinterpret_cast<const float4*>(p);
        const float4 pb = *reinterpret_cast<const float4*>(p + 4);
        const float pv[8] = {pa.x, pa.y, pa.z, pa.w, pb.x, pb.y, pb.z, pb.w};

        float S = 0.0f, P = 0.0f;
        #pragma unroll
        for (int u = 0; u < 8; ++u) {
            S += fexp2(C2P * pv[u]);           // exp(10*p)
            P += pv[u];
        }

        // ---- window pass: 128 elements around mu (covers every e != 1.0f) ----
        int ws = (int)mu - 64;
        ws = ws < 0 ? 0 : (ws > 384 ? 384 : ws);
        const float pw0 = pr[ws + lane];        // L2-hot re-reads, coalesced
        const float pw1 = pr[ws + 64 + lane];
        const float d0 = ((float)ws - mu) + lanef;
        const float d1 = d0 + 64.0f;

        const float g0 = fexp2(d0 * d0 * -NK2);     // gaussian target
        const float e0 = fexp2(g0 * C2P);           // exp(10*g)
        const float g1 = fexp2(d1 * d1 * -NK2);
        const float e1 = fexp2(g1 * C2P);

        float Zw = e0 + e1;                         // window part of Z
        float Tp = e0 * g0 + e1 * g1;               // T' = sum e*g  (T = 10*T')
        float Pd = P + (e0 - 1.0f) * pw0 + (e1 - 1.0f) * pw1;  // P + sum (e-1)*p = D

        // ---- wave reduction of 4 scalars ----
        #pragma unroll
        for (int off = 1; off < 64; off <<= 1) {
            S  += __shfl_xor(S,  off, 64);
            Zw += __shfl_xor(Zw, off, 64);
            Tp += __shfl_xor(Tp, off, 64);
            Pd += __shfl_xor(Pd, off, 64);
        }

        const float Z = 384.0f + Zw;                // far-field e == 1.0 exactly
        const float loss = 10.0f * (Tp - Pd) / Z + __logf(S) - __logf(Z);
        acc += w * loss;
    }

    acc *= (1.0f / (512.0f * 133.0f));
    if (lane == 0) lds[wave] = acc;
    __syncthreads();
    if (threadIdx.x == 0)
        partials[blockIdx.x] = lds[0] + lds[1] + lds[2] + lds[3];
}

__global__ __launch_bounds__(256) void rtmcc_reduce_kernel(
    const float* __restrict__ partials, float* __restrict__ out)
{
    __shared__ float lds[4];
    float s = 0.0f;
    for (int i = threadIdx.x; i < NBLOCKS; i += 256) s += partials[i];
    #pragma unroll
    for (int off = 1; off < 64; off <<= 1) s += __shfl_xor(s, off, 64);
    if ((threadIdx.x & 63) == 0) lds[threadIdx.x >> 6] = s;
    __syncthreads();
    if (threadIdx.x == 0) out[0] = lds[0] + lds[1] + lds[2] + lds[3];
}

extern "C" void kernel_launch(void* const* d_in, const int* in_sizes, int n_in,
                              void* d_out, int out_size, void* d_ws, size_t ws_size,
                              hipStream_t stream) {
    const float* pred = (const float*)d_in[0];   // (256,133,1024) fp32
    const float* kpts = (const float*)d_in[1];   // (256,133,3) fp32
    float* out = (float*)d_out;
    float* partials = (float*)d_ws;

    rtmcc_partial_kernel<<<NBLOCKS, 256, 0, stream>>>(pred, kpts, partials);
    rtmcc_reduce_kernel<<<1, 256, 0, stream>>>(partials, out);
}